// Round 3
// baseline (600.231 us; speedup 1.0000x reference)
//
#include <hip/hip_runtime.h>

// ---------- problem constants ----------
#define HH 96
#define WW 96
#define NPIX (HH*WW)        // 9216
#define CC 64
#define CH 32               // C/2
#define BB 2
#define NKV 144             // NPIX / 64

typedef short bh8 __attribute__((ext_vector_type(8)));
typedef float f32x4 __attribute__((ext_vector_type(4)));
typedef uint2 __attribute__((may_alias)) u2ma;
typedef float4 __attribute__((may_alias)) f4ma;

union FragU { bh8 v; uint2 q[2]; unsigned short u[8]; };

static __device__ __forceinline__ unsigned short f2b(float f){
    union { float f; unsigned int i; } v; v.f = f;
    unsigned int x = v.i;
    unsigned int r = (x + 0x7fffu + ((x >> 16) & 1u)) >> 16;   // RNE, finite values only
    return (unsigned short)r;
}

// ---------- kernel 1: conv3x3 + bias + PReLU for both modalities ----------
// grid (6,6,16): z = ((mod*2 + b)*4 + cq), block 256 = 16x16 pixels
__global__ __launch_bounds__(256) void k_trunk1(
    const float* __restrict__ rgb, const float* __restrict__ dep,
    const float* __restrict__ w1, const float* __restrict__ b1,
    const float* __restrict__ a1p, float* __restrict__ t)
{
    __shared__ float xt[18][20];
    int z   = blockIdx.z;
    int cq  = z & 3;
    int mb  = z >> 2;
    int b   = mb & 1;
    int mod = mb >> 1;
    int tx = threadIdx.x & 15, ty = threadIdx.x >> 4;
    int h0 = blockIdx.y * 16, w0 = blockIdx.x * 16;
    const float* x = (mod ? dep : rgb) + (size_t)b * CC * NPIX;
    float a1 = a1p[0];

    float acc[16];
    #pragma unroll
    for (int i = 0; i < 16; ++i) acc[i] = b1[cq*16 + i];

    for (int ci = 0; ci < CC; ++ci){
        __syncthreads();
        for (int idx = threadIdx.x; idx < 18*18; idx += 256){
            int r = idx / 18, c = idx % 18;
            int gh = h0 + r - 1, gw = w0 + c - 1;
            float v = 0.f;
            if (gh >= 0 && gh < HH && gw >= 0 && gw < WW)
                v = x[ci * NPIX + gh * WW + gw];
            xt[r][c] = v;
        }
        __syncthreads();
        float nb[9];
        #pragma unroll
        for (int dy = 0; dy < 3; ++dy)
            #pragma unroll
            for (int dx = 0; dx < 3; ++dx)
                nb[dy*3+dx] = xt[ty+dy][tx+dx];
        // w1 flat [co][ci][3][3]; uniform pointer -> scalar loads
        const float* wp = w1 + (size_t)cq * 16 * 576 + ci * 9;
        #pragma unroll
        for (int co = 0; co < 16; ++co){
            float s = 0.f;
            #pragma unroll
            for (int k = 0; k < 9; ++k) s = fmaf(nb[k], wp[co*576 + k], s);
            acc[co] += s;
        }
    }
    size_t tb = (size_t)(mod*2 + b) * CC * NPIX;
    int pix = (h0 + ty) * WW + (w0 + tx);
    #pragma unroll
    for (int i = 0; i < 16; ++i){
        float v = acc[i];
        v = (v >= 0.f) ? v : a1 * v;
        t[tb + (size_t)(cq*16 + i) * NPIX + pix] = v;
    }
}

// ---------- kernel 2: conv1x1+PReLU trunks + 3 projections ----------
// block 256 = 64 pixels x 4 cout-groups; grid 288
__global__ __launch_bounds__(256) void k_trunk2(
    const float* __restrict__ t,
    const float* __restrict__ w2, const float* __restrict__ b2,
    const float* __restrict__ a2p,
    const float* __restrict__ wch1, const float* __restrict__ wch2,
    const float* __restrict__ wch3,
    float* __restrict__ d0, unsigned short* __restrict__ c1t,
    unsigned short* __restrict__ d1, unsigned short* __restrict__ d2t)
{
    __shared__ float w2s[64][64];                            // [co][ci]
    __shared__ float wc1[32][64], wc2[32][64], wc3[32][64];  // [co2][ci]
    __shared__ float b2s[64];
    __shared__ float c0buf[64][65];                          // [pixel][ci], padded

    int tid = threadIdx.x;
    for (int i = tid; i < 4096; i += 256) w2s[i >> 6][i & 63] = w2[i];
    for (int i = tid; i < 2048; i += 256){
        int co2 = i >> 6, ci = i & 63;
        wc1[co2][ci] = wch1[i];
        wc2[co2][ci] = wch2[i];
        wc3[co2][ci] = wch3[i];
    }
    if (tid < 64) b2s[tid] = b2[tid];
    float a2 = a2p[0];
    __syncthreads();

    int pl = tid & 63, grp = tid >> 6;
    int P = blockIdx.x * 64 + pl;
    int b = P / NPIX, p = P % NPIX;

    for (int mod = 0; mod < 2; ++mod){
        const float* tp = t + (size_t)(mod*2 + b) * CC * NPIX + p;
        float acc[16];
        #pragma unroll
        for (int i = 0; i < 16; ++i) acc[i] = 0.f;
        for (int ci = 0; ci < 64; ++ci){
            float x = tp[ci * NPIX];
            #pragma unroll
            for (int i = 0; i < 16; ++i) acc[i] = fmaf(x, w2s[grp*16 + i][ci], acc[i]);
        }
        float c0v[16];
        #pragma unroll
        for (int i = 0; i < 16; ++i){
            float v = acc[i] + b2s[grp*16 + i];
            c0v[i] = (v >= 0.f) ? v : a2 * v;
        }
        __syncthreads();                       // protect c0buf from previous pass readers
        #pragma unroll
        for (int i = 0; i < 16; ++i) c0buf[pl][grp*16 + i] = c0v[i];
        __syncthreads();

        if (mod == 0){
            float ca[8];
            #pragma unroll
            for (int j = 0; j < 8; ++j) ca[j] = 0.f;
            for (int ci = 0; ci < 64; ++ci){
                float xc = c0buf[pl][ci];
                #pragma unroll
                for (int j = 0; j < 8; ++j) ca[j] = fmaf(xc, wc1[grp*8 + j][ci], ca[j]);
            }
            #pragma unroll
            for (int j = 0; j < 8; ++j)
                c1t[((size_t)b * CH + grp*8 + j) * NPIX + p] = f2b(ca[j]);
        } else {
            #pragma unroll
            for (int i = 0; i < 16; ++i)
                d0[((size_t)b * CC + grp*16 + i) * NPIX + p] = c0v[i];
            float ca[8], cb[8];
            #pragma unroll
            for (int j = 0; j < 8; ++j){ ca[j] = 0.f; cb[j] = 0.f; }
            for (int ci = 0; ci < 64; ++ci){
                float xc = c0buf[pl][ci];
                #pragma unroll
                for (int j = 0; j < 8; ++j){
                    ca[j] = fmaf(xc, wc2[grp*8 + j][ci], ca[j]);
                    cb[j] = fmaf(xc, wc3[grp*8 + j][ci], cb[j]);
                }
            }
            #pragma unroll
            for (int j = 0; j < 8; ++j){
                d1 [((size_t)b * NPIX + p) * CH + grp*8 + j] = f2b(ca[j]);
                d2t[((size_t)b * NPIX + p) * CH + grp*8 + j] = f2b(cb[j]);
            }
        }
    }
}

// ---------- kernel 3: flash attention (no scale), MFMA 16x16x32 bf16 ----------
// grid (144, B); block 256 = 4 waves; wave handles 16 query rows; KBLK = 64
__global__ __launch_bounds__(256) void k_attn(
    const unsigned short* __restrict__ d1, const unsigned short* __restrict__ d2t,
    const unsigned short* __restrict__ c1t, float* __restrict__ O)
{
    __shared__ unsigned short plds[4][16][72];   // per-wave P tile, padded rows (144B)
    int b    = blockIdx.y;
    int wid  = threadIdx.x >> 6;
    int lane = threadIdx.x & 63;
    int l16  = lane & 15;
    int lg   = lane >> 4;                 // 0..3
    int q0   = (blockIdx.x * 4 + wid) * 16;

    FragU qf;
    {
        const unsigned short* qp = d1 + ((size_t)b * NPIX + q0 + l16) * CH + lg * 4;
        qf.q[0] = *(const u2ma*)qp;
        qf.q[1] = *(const u2ma*)(qp + 16);
    }

    f32x4 o0 = {0.f,0.f,0.f,0.f}, o1 = {0.f,0.f,0.f,0.f};
    float m[4], lsum[4];
    #pragma unroll
    for (int i = 0; i < 4; ++i){ m[i] = -1e30f; lsum[i] = 0.f; }

    for (int kt = 0; kt < NKV; ++kt){
        int kb = kt * 64;
        // --- load K frags (B for QK^T) and V frags (B for PV) up front ---
        FragU kf[4];
        #pragma unroll
        for (int j = 0; j < 4; ++j){
            const unsigned short* kp = d2t + ((size_t)b * NPIX + kb + j*16 + l16) * CH + lg * 4;
            kf[j].q[0] = *(const u2ma*)kp;
            kf[j].q[1] = *(const u2ma*)(kp + 16);
        }
        FragU vf[2][2];   // [ks][jt]
        #pragma unroll
        for (int ks = 0; ks < 2; ++ks)
            #pragma unroll
            for (int jt = 0; jt < 2; ++jt){
                const unsigned short* vp =
                    c1t + ((size_t)b * CH + jt*16 + l16) * NPIX + kb + ks*32 + lg*4;
                vf[ks][jt].q[0] = *(const u2ma*)vp;
                vf[ks][jt].q[1] = *(const u2ma*)(vp + 16);
            }
        // --- S = Q K ---
        f32x4 s[4];
        #pragma unroll
        for (int j = 0; j < 4; ++j){
            f32x4 z = {0.f,0.f,0.f,0.f};
            s[j] = __builtin_amdgcn_mfma_f32_16x16x32_bf16(qf.v, kf[j].v, z, 0, 0, 0);
        }
        // --- online softmax ---
        float pm[4];
        #pragma unroll
        for (int i = 0; i < 4; ++i){
            float v = fmaxf(fmaxf(s[0][i], s[1][i]), fmaxf(s[2][i], s[3][i]));
            v = fmaxf(v, __shfl_xor(v, 1));
            v = fmaxf(v, __shfl_xor(v, 2));
            v = fmaxf(v, __shfl_xor(v, 4));
            v = fmaxf(v, __shfl_xor(v, 8));
            pm[i] = v;
        }
        float al[4];
        #pragma unroll
        for (int i = 0; i < 4; ++i){
            float mn = fmaxf(m[i], pm[i]);
            al[i] = __expf(m[i] - mn);
            m[i] = mn;
        }
        float ps[4] = {0.f,0.f,0.f,0.f};
        #pragma unroll
        for (int j = 0; j < 4; ++j){
            #pragma unroll
            for (int i = 0; i < 4; ++i){
                float e = __expf(s[j][i] - m[i]);
                ps[i] += e;
                plds[wid][lg*4 + i][j*16 + l16] = f2b(e);
            }
        }
        #pragma unroll
        for (int i = 0; i < 4; ++i){
            float tsum = ps[i];
            tsum += __shfl_xor(tsum, 1);
            tsum += __shfl_xor(tsum, 2);
            tsum += __shfl_xor(tsum, 4);
            tsum += __shfl_xor(tsum, 8);
            lsum[i] = lsum[i] * al[i] + tsum;
            o0[i] *= al[i];
            o1[i] *= al[i];
        }
        asm volatile("" ::: "memory");   // order P writes before P reads
        // --- O += P V ---
        #pragma unroll
        for (int ks = 0; ks < 2; ++ks){
            FragU pa;
            const unsigned short* pr = &plds[wid][l16][ks*32 + lg*4];
            pa.q[0] = *(const u2ma*)pr;
            pa.q[1] = *(const u2ma*)(pr + 16);
            o0 = __builtin_amdgcn_mfma_f32_16x16x32_bf16(pa.v, vf[ks][0].v, o0, 0, 0, 0);
            o1 = __builtin_amdgcn_mfma_f32_16x16x32_bf16(pa.v, vf[ks][1].v, o1, 0, 0, 0);
        }
    }
    #pragma unroll
    for (int i = 0; i < 4; ++i){
        float inv = 1.f / lsum[i];
        int q = q0 + lg*4 + i;
        float* op = O + ((size_t)b * NPIX + q) * CH;
        op[l16]      = o0[i] * inv;
        op[16 + l16] = o1[i] * inv;
    }
}

// ---------- kernel 4: 1x1 conv (32->64) + residual add ----------
// block 256 = 64 pixels x 4 cout-groups; grid 288
__global__ __launch_bounds__(256) void k_final(
    const float* __restrict__ O, const float* __restrict__ wch4,
    const float* __restrict__ d0, float* __restrict__ out)
{
    __shared__ float w4s[64][32];   // [co][d]
    int tid = threadIdx.x;
    for (int i = tid; i < 2048; i += 256) w4s[i >> 5][i & 31] = wch4[i];
    __syncthreads();
    int pl = tid & 63, grp = tid >> 6;
    int P = blockIdx.x * 64 + pl;
    int b = P / NPIX, p = P % NPIX;

    float ob[32];
    const f4ma* ov = (const f4ma*)(O + (size_t)P * CH);
    #pragma unroll
    for (int i = 0; i < 8; ++i){
        float4 v = ov[i];
        ob[i*4+0] = v.x; ob[i*4+1] = v.y; ob[i*4+2] = v.z; ob[i*4+3] = v.w;
    }

    float acc[16];
    #pragma unroll
    for (int i = 0; i < 16; ++i) acc[i] = 0.f;
    #pragma unroll
    for (int d = 0; d < 32; ++d){
        float x = ob[d];
        #pragma unroll
        for (int i = 0; i < 16; ++i) acc[i] = fmaf(x, w4s[grp*16 + i][d], acc[i]);
    }
    #pragma unroll
    for (int i = 0; i < 16; ++i){
        size_t idx = ((size_t)b * CC + grp*16 + i) * NPIX + p;
        out[idx] = acc[i] + d0[idx];
    }
}

// ---------- launch ----------
extern "C" void kernel_launch(void* const* d_in, const int* in_sizes, int n_in,
                              void* d_out, int out_size, void* d_ws, size_t ws_size,
                              hipStream_t stream) {
    const float* rgb  = (const float*)d_in[0];
    const float* dep  = (const float*)d_in[1];
    const float* w1   = (const float*)d_in[2];
    const float* b1   = (const float*)d_in[3];
    const float* a1   = (const float*)d_in[4];
    const float* w2   = (const float*)d_in[5];
    const float* b2   = (const float*)d_in[6];
    const float* a2   = (const float*)d_in[7];
    const float* wch1 = (const float*)d_in[8];
    const float* wch2 = (const float*)d_in[9];
    const float* wch3 = (const float*)d_in[10];
    const float* wch4 = (const float*)d_in[11];

    char* ws = (char*)d_ws;
    float* t             = (float*)(ws);                          //  9,437,184 B
    float* d0            = (float*)(ws + 9437184);                //  4,718,592 B
    unsigned short* c1t  = (unsigned short*)(ws + 14155776);      //  1,179,648 B
    unsigned short* d1   = (unsigned short*)(ws + 15335424);      //  1,179,648 B
    unsigned short* d2t  = (unsigned short*)(ws + 16515072);      //  1,179,648 B
    float* Obuf          = (float*)(ws + 17694720);               //  2,359,296 B
    // total ws use: 20,054,016 B

    k_trunk1<<<dim3(6,6,16), 256, 0, stream>>>(rgb, dep, w1, b1, a1, t);
    k_trunk2<<<288, 256, 0, stream>>>(t, w2, b2, a2, wch1, wch2, wch3, d0, c1t, d1, d2t);
    k_attn  <<<dim3(NKV, BB), 256, 0, stream>>>(d1, d2t, c1t, Obuf);
    k_final <<<288, 256, 0, stream>>>(Obuf, wch4, d0, (float*)d_out);
}

// Round 4
// 457.148 us; speedup vs baseline: 1.3130x; 1.3130x over previous
//
#include <hip/hip_runtime.h>

// ---------- problem constants ----------
#define HH 96
#define WW 96
#define NPIX (HH*WW)        // 9216
#define CC 64
#define CH 32               // C/2
#define BB 2
#define NKV 144             // NPIX / 64
#define NSPLIT 6
#define KPT (NKV/NSPLIT)    // 24 KV tiles per split

typedef short bh8 __attribute__((ext_vector_type(8)));
typedef float f32x4 __attribute__((ext_vector_type(4)));
typedef uint2 __attribute__((may_alias)) u2ma;
typedef float4 __attribute__((may_alias)) f4ma;

union FragU { bh8 v; uint2 q[2]; unsigned short u[8]; };

static __device__ __forceinline__ unsigned short f2b(float f){
    union { float f; unsigned int i; } v; v.f = f;
    unsigned int x = v.i;
    unsigned int r = (x + 0x7fffu + ((x >> 16) & 1u)) >> 16;   // RNE, finite values only
    return (unsigned short)r;
}

// ---------- kernel 1: conv3x3 + bias + PReLU for both modalities ----------
// grid (6,6,16): z = ((mod*2 + b)*4 + cq), block 256 = 16x16 pixels
__global__ __launch_bounds__(256) void k_trunk1(
    const float* __restrict__ rgb, const float* __restrict__ dep,
    const float* __restrict__ w1, const float* __restrict__ b1,
    const float* __restrict__ a1p, float* __restrict__ t)
{
    __shared__ float xt[18][20];
    int z   = blockIdx.z;
    int cq  = z & 3;
    int mb  = z >> 2;
    int b   = mb & 1;
    int mod = mb >> 1;
    int tx = threadIdx.x & 15, ty = threadIdx.x >> 4;
    int h0 = blockIdx.y * 16, w0 = blockIdx.x * 16;
    const float* x = (mod ? dep : rgb) + (size_t)b * CC * NPIX;
    float a1 = a1p[0];

    float acc[16];
    #pragma unroll
    for (int i = 0; i < 16; ++i) acc[i] = b1[cq*16 + i];

    for (int ci = 0; ci < CC; ++ci){
        __syncthreads();
        for (int idx = threadIdx.x; idx < 18*18; idx += 256){
            int r = idx / 18, c = idx % 18;
            int gh = h0 + r - 1, gw = w0 + c - 1;
            float v = 0.f;
            if (gh >= 0 && gh < HH && gw >= 0 && gw < WW)
                v = x[ci * NPIX + gh * WW + gw];
            xt[r][c] = v;
        }
        __syncthreads();
        float nb[9];
        #pragma unroll
        for (int dy = 0; dy < 3; ++dy)
            #pragma unroll
            for (int dx = 0; dx < 3; ++dx)
                nb[dy*3+dx] = xt[ty+dy][tx+dx];
        // w1 flat [co][ci][3][3]; uniform pointer -> scalar loads
        const float* wp = w1 + (size_t)cq * 16 * 576 + ci * 9;
        #pragma unroll
        for (int co = 0; co < 16; ++co){
            float s = 0.f;
            #pragma unroll
            for (int k = 0; k < 9; ++k) s = fmaf(nb[k], wp[co*576 + k], s);
            acc[co] += s;
        }
    }
    size_t tb = (size_t)(mod*2 + b) * CC * NPIX;
    int pix = (h0 + ty) * WW + (w0 + tx);
    #pragma unroll
    for (int i = 0; i < 16; ++i){
        float v = acc[i];
        v = (v >= 0.f) ? v : a1 * v;
        t[tb + (size_t)(cq*16 + i) * NPIX + pix] = v;
    }
}

// ---------- kernel 2: conv1x1+PReLU trunks + 3 projections ----------
// block 256 = 64 pixels x 4 cout-groups; grid 288
__global__ __launch_bounds__(256) void k_trunk2(
    const float* __restrict__ t,
    const float* __restrict__ w2, const float* __restrict__ b2,
    const float* __restrict__ a2p,
    const float* __restrict__ wch1, const float* __restrict__ wch2,
    const float* __restrict__ wch3,
    float* __restrict__ d0, unsigned short* __restrict__ c1t,
    unsigned short* __restrict__ d1, unsigned short* __restrict__ d2t)
{
    __shared__ float w2s[64][64];                            // [co][ci]
    __shared__ float wc1[32][64], wc2[32][64], wc3[32][64];  // [co2][ci]
    __shared__ float b2s[64];
    __shared__ float c0buf[64][65];                          // [pixel][ci], padded

    int tid = threadIdx.x;
    for (int i = tid; i < 4096; i += 256) w2s[i >> 6][i & 63] = w2[i];
    for (int i = tid; i < 2048; i += 256){
        int co2 = i >> 6, ci = i & 63;
        wc1[co2][ci] = wch1[i];
        wc2[co2][ci] = wch2[i];
        wc3[co2][ci] = wch3[i];
    }
    if (tid < 64) b2s[tid] = b2[tid];
    float a2 = a2p[0];
    __syncthreads();

    int pl = tid & 63, grp = tid >> 6;
    int P = blockIdx.x * 64 + pl;
    int b = P / NPIX, p = P % NPIX;

    for (int mod = 0; mod < 2; ++mod){
        const float* tp = t + (size_t)(mod*2 + b) * CC * NPIX + p;
        float acc[16];
        #pragma unroll
        for (int i = 0; i < 16; ++i) acc[i] = 0.f;
        for (int ci = 0; ci < 64; ++ci){
            float x = tp[ci * NPIX];
            #pragma unroll
            for (int i = 0; i < 16; ++i) acc[i] = fmaf(x, w2s[grp*16 + i][ci], acc[i]);
        }
        float c0v[16];
        #pragma unroll
        for (int i = 0; i < 16; ++i){
            float v = acc[i] + b2s[grp*16 + i];
            c0v[i] = (v >= 0.f) ? v : a2 * v;
        }
        __syncthreads();                       // protect c0buf from previous pass readers
        #pragma unroll
        for (int i = 0; i < 16; ++i) c0buf[pl][grp*16 + i] = c0v[i];
        __syncthreads();

        if (mod == 0){
            float ca[8];
            #pragma unroll
            for (int j = 0; j < 8; ++j) ca[j] = 0.f;
            for (int ci = 0; ci < 64; ++ci){
                float xc = c0buf[pl][ci];
                #pragma unroll
                for (int j = 0; j < 8; ++j) ca[j] = fmaf(xc, wc1[grp*8 + j][ci], ca[j]);
            }
            #pragma unroll
            for (int j = 0; j < 8; ++j)
                c1t[((size_t)b * CH + grp*8 + j) * NPIX + p] = f2b(ca[j]);
        } else {
            #pragma unroll
            for (int i = 0; i < 16; ++i)
                d0[((size_t)b * CC + grp*16 + i) * NPIX + p] = c0v[i];
            float ca[8], cb[8];
            #pragma unroll
            for (int j = 0; j < 8; ++j){ ca[j] = 0.f; cb[j] = 0.f; }
            for (int ci = 0; ci < 64; ++ci){
                float xc = c0buf[pl][ci];
                #pragma unroll
                for (int j = 0; j < 8; ++j){
                    ca[j] = fmaf(xc, wc2[grp*8 + j][ci], ca[j]);
                    cb[j] = fmaf(xc, wc3[grp*8 + j][ci], cb[j]);
                }
            }
            #pragma unroll
            for (int j = 0; j < 8; ++j){
                d1 [((size_t)b * NPIX + p) * CH + grp*8 + j] = f2b(ca[j]);
                d2t[((size_t)b * NPIX + p) * CH + grp*8 + j] = f2b(cb[j]);
            }
        }
    }
}

// ---------- kernel 3: flash attention, K-split partials ----------
// grid (144, B, NSPLIT); block 256 = 4 waves; wave = 16 query rows; KBLK = 64
__global__ __launch_bounds__(256) void k_attn(
    const unsigned short* __restrict__ d1, const unsigned short* __restrict__ d2t,
    const unsigned short* __restrict__ c1t, float* __restrict__ Opart,
    float* __restrict__ mpart, float* __restrict__ lpart)
{
    __shared__ unsigned short plds[4][16][72];   // per-wave P tile, padded rows (144B)
    int b    = blockIdx.y;
    int sp   = blockIdx.z;
    int wid  = threadIdx.x >> 6;
    int lane = threadIdx.x & 63;
    int l16  = lane & 15;
    int lg   = lane >> 4;                 // 0..3
    int q0   = (blockIdx.x * 4 + wid) * 16;

    FragU qf;
    {
        const unsigned short* qp = d1 + ((size_t)b * NPIX + q0 + l16) * CH + lg * 4;
        qf.q[0] = *(const u2ma*)qp;
        qf.q[1] = *(const u2ma*)(qp + 16);
    }

    f32x4 o0 = {0.f,0.f,0.f,0.f}, o1 = {0.f,0.f,0.f,0.f};
    float m[4], lsum[4];
    #pragma unroll
    for (int i = 0; i < 4; ++i){ m[i] = -1e30f; lsum[i] = 0.f; }

    for (int kt = sp * KPT; kt < (sp + 1) * KPT; ++kt){
        int kb = kt * 64;
        // --- load K frags (B for QK^T) and V frags (B for PV) up front ---
        FragU kf[4];
        #pragma unroll
        for (int j = 0; j < 4; ++j){
            const unsigned short* kp = d2t + ((size_t)b * NPIX + kb + j*16 + l16) * CH + lg * 4;
            kf[j].q[0] = *(const u2ma*)kp;
            kf[j].q[1] = *(const u2ma*)(kp + 16);
        }
        FragU vf[2][2];   // [ks][jt]
        #pragma unroll
        for (int ks = 0; ks < 2; ++ks)
            #pragma unroll
            for (int jt = 0; jt < 2; ++jt){
                const unsigned short* vp =
                    c1t + ((size_t)b * CH + jt*16 + l16) * NPIX + kb + ks*32 + lg*4;
                vf[ks][jt].q[0] = *(const u2ma*)vp;
                vf[ks][jt].q[1] = *(const u2ma*)(vp + 16);
            }
        // --- S = Q K ---
        f32x4 s[4];
        #pragma unroll
        for (int j = 0; j < 4; ++j){
            f32x4 z = {0.f,0.f,0.f,0.f};
            s[j] = __builtin_amdgcn_mfma_f32_16x16x32_bf16(qf.v, kf[j].v, z, 0, 0, 0);
        }
        // --- online softmax ---
        float pm[4];
        #pragma unroll
        for (int i = 0; i < 4; ++i){
            float v = fmaxf(fmaxf(s[0][i], s[1][i]), fmaxf(s[2][i], s[3][i]));
            v = fmaxf(v, __shfl_xor(v, 1));
            v = fmaxf(v, __shfl_xor(v, 2));
            v = fmaxf(v, __shfl_xor(v, 4));
            v = fmaxf(v, __shfl_xor(v, 8));
            pm[i] = v;
        }
        float al[4];
        #pragma unroll
        for (int i = 0; i < 4; ++i){
            float mn = fmaxf(m[i], pm[i]);
            al[i] = __expf(m[i] - mn);
            m[i] = mn;
        }
        float ps[4] = {0.f,0.f,0.f,0.f};
        #pragma unroll
        for (int j = 0; j < 4; ++j){
            #pragma unroll
            for (int i = 0; i < 4; ++i){
                float e = __expf(s[j][i] - m[i]);
                ps[i] += e;
                plds[wid][lg*4 + i][j*16 + l16] = f2b(e);
            }
        }
        #pragma unroll
        for (int i = 0; i < 4; ++i){
            float tsum = ps[i];
            tsum += __shfl_xor(tsum, 1);
            tsum += __shfl_xor(tsum, 2);
            tsum += __shfl_xor(tsum, 4);
            tsum += __shfl_xor(tsum, 8);
            lsum[i] = lsum[i] * al[i] + tsum;
            o0[i] *= al[i];
            o1[i] *= al[i];
        }
        asm volatile("" ::: "memory");   // order P writes before P reads
        // --- O += P V ---
        #pragma unroll
        for (int ks = 0; ks < 2; ++ks){
            FragU pa;
            const unsigned short* pr = &plds[wid][l16][ks*32 + lg*4];
            pa.q[0] = *(const u2ma*)pr;
            pa.q[1] = *(const u2ma*)(pr + 16);
            o0 = __builtin_amdgcn_mfma_f32_16x16x32_bf16(pa.v, vf[ks][0].v, o0, 0, 0, 0);
            o1 = __builtin_amdgcn_mfma_f32_16x16x32_bf16(pa.v, vf[ks][1].v, o1, 0, 0, 0);
        }
    }
    // --- write unnormalized partials ---
    size_t pbase = ((size_t)(sp * BB + b) * NPIX);
    #pragma unroll
    for (int i = 0; i < 4; ++i){
        int q = q0 + lg*4 + i;
        float* op = Opart + (pbase + q) * CH;
        op[l16]      = o0[i];
        op[16 + l16] = o1[i];
        if (l16 == 0){
            mpart[pbase + q] = m[i];
            lpart[pbase + q] = lsum[i];
        }
    }
}

// ---------- kernel 3b: combine K-split partials ----------
// block 256 = 8 rows x 32 cols; grid 2304
__global__ __launch_bounds__(256) void k_comb(
    const float* __restrict__ Opart, const float* __restrict__ mpart,
    const float* __restrict__ lpart, float* __restrict__ Obuf)
{
    int c   = threadIdx.x & 31;
    int row = blockIdx.x * 8 + (threadIdx.x >> 5);   // 0 .. BB*NPIX-1
    int b   = row / NPIX, q = row % NPIX;

    float mv[NSPLIT];
    float M = -1e30f;
    #pragma unroll
    for (int s = 0; s < NSPLIT; ++s){
        mv[s] = mpart[(size_t)(s * BB + b) * NPIX + q];
        M = fmaxf(M, mv[s]);
    }
    float L = 0.f, acc = 0.f;
    #pragma unroll
    for (int s = 0; s < NSPLIT; ++s){
        float w = __expf(mv[s] - M);
        L   += w * lpart[(size_t)(s * BB + b) * NPIX + q];
        acc += w * Opart[((size_t)(s * BB + b) * NPIX + q) * CH + c];
    }
    Obuf[((size_t)b * NPIX + q) * CH + c] = acc / L;
}

// ---------- kernel 4: 1x1 conv (32->64) + residual add ----------
// block 256 = 64 pixels x 4 cout-groups; grid 288
__global__ __launch_bounds__(256) void k_final(
    const float* __restrict__ O, const float* __restrict__ wch4,
    const float* __restrict__ d0, float* __restrict__ out)
{
    __shared__ float w4s[64][32];   // [co][d]
    int tid = threadIdx.x;
    for (int i = tid; i < 2048; i += 256) w4s[i >> 5][i & 31] = wch4[i];
    __syncthreads();
    int pl = tid & 63, grp = tid >> 6;
    int P = blockIdx.x * 64 + pl;
    int b = P / NPIX, p = P % NPIX;

    float ob[32];
    const f4ma* ov = (const f4ma*)(O + (size_t)P * CH);
    #pragma unroll
    for (int i = 0; i < 8; ++i){
        float4 v = ov[i];
        ob[i*4+0] = v.x; ob[i*4+1] = v.y; ob[i*4+2] = v.z; ob[i*4+3] = v.w;
    }

    float acc[16];
    #pragma unroll
    for (int i = 0; i < 16; ++i) acc[i] = 0.f;
    #pragma unroll
    for (int d = 0; d < 32; ++d){
        float x = ob[d];
        #pragma unroll
        for (int i = 0; i < 16; ++i) acc[i] = fmaf(x, w4s[grp*16 + i][d], acc[i]);
    }
    #pragma unroll
    for (int i = 0; i < 16; ++i){
        size_t idx = ((size_t)b * CC + grp*16 + i) * NPIX + p;
        out[idx] = acc[i] + d0[idx];
    }
}

// ---------- launch ----------
extern "C" void kernel_launch(void* const* d_in, const int* in_sizes, int n_in,
                              void* d_out, int out_size, void* d_ws, size_t ws_size,
                              hipStream_t stream) {
    const float* rgb  = (const float*)d_in[0];
    const float* dep  = (const float*)d_in[1];
    const float* w1   = (const float*)d_in[2];
    const float* b1   = (const float*)d_in[3];
    const float* a1   = (const float*)d_in[4];
    const float* w2   = (const float*)d_in[5];
    const float* b2   = (const float*)d_in[6];
    const float* a2   = (const float*)d_in[7];
    const float* wch1 = (const float*)d_in[8];
    const float* wch2 = (const float*)d_in[9];
    const float* wch3 = (const float*)d_in[10];
    const float* wch4 = (const float*)d_in[11];

    char* ws = (char*)d_ws;
    float* t             = (float*)(ws);                          //  9,437,184 B
    float* d0            = (float*)(ws + 9437184);                //  4,718,592 B
    unsigned short* c1t  = (unsigned short*)(ws + 14155776);      //  1,179,648 B
    unsigned short* d1   = (unsigned short*)(ws + 15335424);      //  1,179,648 B
    unsigned short* d2t  = (unsigned short*)(ws + 16515072);      //  1,179,648 B
    float* Obuf          = (float*)(ws + 17694720);               //  2,359,296 B
    float* Opart         = (float*)(ws + 20054016);               // 14,155,776 B
    float* mpart         = (float*)(ws + 34209792);               //    442,368 B
    float* lpart         = (float*)(ws + 34652160);               //    442,368 B
    // total ws use: 35,094,528 B

    k_trunk1<<<dim3(6,6,16), 256, 0, stream>>>(rgb, dep, w1, b1, a1, t);
    k_trunk2<<<288, 256, 0, stream>>>(t, w2, b2, a2, wch1, wch2, wch3, d0, c1t, d1, d2t);
    k_attn  <<<dim3(NKV, BB, NSPLIT), 256, 0, stream>>>(d1, d2t, c1t, Opart, mpart, lpart);
    k_comb  <<<BB*NPIX/8, 256, 0, stream>>>(Opart, mpart, lpart, Obuf);
    k_final <<<288, 256, 0, stream>>>(Obuf, wch4, d0, (float*)d_out);
}